// Round 1
// baseline (998.357 us; speedup 1.0000x reference)
//
#include <hip/hip_runtime.h>
#include <hip/hip_bf16.h>
#include <stdint.h>

// Problem constants (from setup_inputs)
#define T_DIM 2048
#define N_DIM 16
#define I_DIM 1024
#define H_DIM 2048
#define O_DIM 1024
#define K_TAPS 12
#define MROWS (N_DIM * T_DIM)   // 32768 rows of (n,t)
#define BN_EPS 1e-5f

typedef __attribute__((ext_vector_type(8))) short bf16x8;
typedef __attribute__((ext_vector_type(4))) float f32x4;

__device__ __forceinline__ unsigned short f2bf_rne(float f) {
    union { float f; unsigned u; } v; v.f = f;
    unsigned u = v.u;
    unsigned r = u + 0x7fffu + ((u >> 16) & 1u);
    return (unsigned short)(r >> 16);
}

__device__ __forceinline__ float bf2f(unsigned short x) {
    union { unsigned u; float f; } v; v.u = ((unsigned)x) << 16; return v.f;
}

// ---------------- fp32 -> bf16 conversion (vectorized x4) ----------------
__global__ void cvt_kernel(const float* __restrict__ in, unsigned short* __restrict__ out, int n4) {
    int i = blockIdx.x * blockDim.x + threadIdx.x;
    int stride = gridDim.x * blockDim.x;
    for (; i < n4; i += stride) {
        float4 v = ((const float4*)in)[i];
        ushort4 o;
        o.x = f2bf_rne(v.x); o.y = f2bf_rne(v.y);
        o.z = f2bf_rne(v.z); o.w = f2bf_rne(v.w);
        ((ushort4*)out)[i] = o;
    }
}

// ---------------- 128x128 bf16 MFMA GEMM, C = A * B^T ----------------
// A: [M, Kd] bf16 (PERM=1: output row r=n*T+t reads input row t*N+n)
// B: [Ncols, Kd] bf16
// EPI=0: store bf16 to Cout (ushort)
// EPI=1: store fp32 relu(acc + bias[col]) to Cout (float)
__device__ __forceinline__ void gload_lds16(const void* g, void* l) {
    __builtin_amdgcn_global_load_lds(
        (const __attribute__((address_space(1))) unsigned int*)g,
        (__attribute__((address_space(3))) unsigned int*)l, 16, 0, 0);
}

template<int PERM, int EPI>
__global__ __launch_bounds__(256) void gemm128(
    const unsigned short* __restrict__ A,
    const unsigned short* __restrict__ B,
    void* __restrict__ Cout,
    const float* __restrict__ bias,
    int Kd, int Ncols)
{
    __shared__ unsigned short As[2][128 * 32];
    __shared__ unsigned short Bs[2][128 * 32];

    const int tid = threadIdx.x;
    const long r0 = (long)blockIdx.y * 128;   // output row tile
    const long c0 = (long)blockIdx.x * 128;   // output col tile

    long aBase, aRowStride;
    if (PERM) {
        long n0 = r0 / T_DIM;
        long t0 = r0 % T_DIM;                 // tile stays within one n (T%128==0)
        aBase = (t0 * N_DIM + n0) * (long)Kd;
        aRowStride = (long)N_DIM * Kd;
    } else {
        aBase = r0 * (long)Kd;
        aRowStride = Kd;
    }
    const long bBase = c0 * (long)Kd;

    const int lrow  = tid >> 2;           // 0..63 (row within half-tile)
    const int lcolb = (tid & 3) * 16;     // byte col within 64B row

    f32x4 acc[4][4];
#pragma unroll
    for (int m = 0; m < 4; ++m)
#pragma unroll
        for (int n = 0; n < 4; ++n) acc[m][n] = (f32x4){0.f, 0.f, 0.f, 0.f};

    auto stage = [&](int buf, int kt) {
        const long k0 = (long)kt * 32;
#pragma unroll
        for (int i = 0; i < 2; ++i) {
            int row = i * 64 + lrow;
            const char* g = (const char*)(A + aBase + (long)row * aRowStride + k0) + lcolb;
            char* l = ((char*)&As[buf][0]) + i * 4096 + tid * 16;
            gload_lds16(g, l);
        }
#pragma unroll
        for (int i = 0; i < 2; ++i) {
            int row = i * 64 + lrow;
            const char* g = (const char*)(B + bBase + (long)row * (long)Kd + k0) + lcolb;
            char* l = ((char*)&Bs[buf][0]) + i * 4096 + tid * 16;
            gload_lds16(g, l);
        }
    };

    const int wv   = tid >> 6;            // wave 0..3
    const int lane = tid & 63;
    const int wr   = (wv >> 1) * 64;      // wave row offset
    const int wc   = (wv & 1) * 64;       // wave col offset
    const int fr   = lane & 15;
    const int kg   = (lane >> 4) * 8;     // k-offset (elems) within 32

    const int KT = Kd >> 5;
    int cur = 0;
    stage(0, 0);
    for (int kt = 0; kt < KT; ++kt) {
        __syncthreads();                   // staging of buf `cur` complete everywhere
        if (kt + 1 < KT) stage(cur ^ 1, kt + 1);
        bf16x8 af[4], bfr[4];
#pragma unroll
        for (int m = 0; m < 4; ++m)
            af[m] = *(const bf16x8*)&As[cur][(wr + m * 16 + fr) * 32 + kg];
#pragma unroll
        for (int n = 0; n < 4; ++n)
            bfr[n] = *(const bf16x8*)&Bs[cur][(wc + n * 16 + fr) * 32 + kg];
#pragma unroll
        for (int m = 0; m < 4; ++m)
#pragma unroll
            for (int n = 0; n < 4; ++n)
                acc[m][n] = __builtin_amdgcn_mfma_f32_16x16x32_bf16(af[m], bfr[n], acc[m][n], 0, 0, 0);
        cur ^= 1;
    }

    // C/D layout (m89-verified): col = lane&15, row = (lane>>4)*4 + reg
#pragma unroll
    for (int m = 0; m < 4; ++m) {
        const long orow_base = r0 + wr + m * 16 + ((lane >> 4) * 4);
#pragma unroll
        for (int n = 0; n < 4; ++n) {
            const long ocol = c0 + wc + n * 16 + fr;
#pragma unroll
            for (int j = 0; j < 4; ++j) {
                const long orow = orow_base + j;
                float vv = acc[m][n][j];
                if (EPI == 0) {
                    ((unsigned short*)Cout)[orow * Ncols + ocol] = f2bf_rne(vv);
                } else {
                    vv += bias[ocol];
                    vv = vv > 0.f ? vv : 0.f;
                    ((float*)Cout)[orow * Ncols + ocol] = vv;
                }
            }
        }
    }
}

// ---------------- depthwise dilated conv + BN stats ----------------
// p: [MROWS][H] bf16; p_hatt[r,h] = p[r,h] + sum_k w[k,h]*p[n, t+(k-10)*2, h]
__global__ __launch_bounds__(256) void conv_bn_stats(
    const unsigned short* __restrict__ p,
    const float* __restrict__ w,          // [12][H]
    float* __restrict__ ph_f32,           // output p_hatt (fp32)
    unsigned short* __restrict__ ph_b,    // bf16 copy for GEMM2
    float* __restrict__ sums)             // [2][H] zeroed
{
    const int hg = blockIdx.x & 7;
    const int rc = blockIdx.x >> 3;
    const int h  = hg * 256 + threadIdx.x;

    float wk[K_TAPS];
#pragma unroll
    for (int k = 0; k < K_TAPS; ++k) wk[k] = w[k * H_DIM + h];

    float s1 = 0.f, s2 = 0.f;
    const int rbeg = rc * 128;
    for (int r = rbeg; r < rbeg + 128; ++r) {
        const int t = r & (T_DIM - 1);
        const long base = (long)r * H_DIM + h;
        float acc = bf2f(p[base]);
#pragma unroll
        for (int k = 0; k < K_TAPS; ++k) {
            const int dt = (k - 10) * 2;
            const int tt = t + dt;
            if (tt >= 0 && tt < T_DIM)
                acc += wk[k] * bf2f(p[base + (long)dt * H_DIM]);
        }
        ph_f32[base] = acc;
        ph_b[base] = f2bf_rne(acc);
        s1 += acc; s2 += acc * acc;
    }
    atomicAdd(&sums[h], s1);
    atomicAdd(&sums[H_DIM + h], s2);
}

// ---------------- BN finalize: s = gamma*rsqrt(var+eps); shift = beta - mean*s ----
__global__ void bn_finalize(const float* __restrict__ sums,
                            const float* __restrict__ gamma,
                            const float* __restrict__ beta,
                            float* __restrict__ sshift) {
    int h = blockIdx.x * blockDim.x + threadIdx.x;
    if (h >= H_DIM) return;
    float mean = sums[h] * (1.f / (float)MROWS);
    float var  = sums[H_DIM + h] * (1.f / (float)MROWS) - mean * mean;
    float s = gamma[h] * rsqrtf(var + BN_EPS);
    sshift[h] = s;
    sshift[H_DIM + h] = beta[h] - mean * s;
}

// wu2[o,h] = bf16(wu[o,h] * s[h])
__global__ void scale_wu(const float* __restrict__ wu,
                         const float* __restrict__ sshift,
                         unsigned short* __restrict__ wu2) {
    int idx = blockIdx.x * blockDim.x + threadIdx.x;
    int stride = gridDim.x * blockDim.x;
    for (; idx < O_DIM * H_DIM; idx += stride) {
        int h = idx & (H_DIM - 1);
        wu2[idx] = f2bf_rne(wu[idx] * sshift[h]);
    }
}

// bias2[o] = bu[o] + sum_h shift[h]*wu[o,h]
__global__ __launch_bounds__(256) void bias2_kernel(
    const float* __restrict__ wu,
    const float* __restrict__ sshift,
    const float* __restrict__ bu,
    float* __restrict__ bias2) {
    const int o = blockIdx.x;
    float part = 0.f;
    for (int h = threadIdx.x; h < H_DIM; h += 256)
        part += sshift[H_DIM + h] * wu[(long)o * H_DIM + h];
#pragma unroll
    for (int off = 32; off > 0; off >>= 1) part += __shfl_down(part, off, 64);
    __shared__ float red[4];
    const int wv = threadIdx.x >> 6, lane = threadIdx.x & 63;
    if (lane == 0) red[wv] = part;
    __syncthreads();
    if (threadIdx.x == 0) bias2[o] = bu[o] + red[0] + red[1] + red[2] + red[3];
}

extern "C" void kernel_launch(void* const* d_in, const int* in_sizes, int n_in,
                              void* d_out, int out_size, void* d_ws, size_t ws_size,
                              hipStream_t stream) {
    const float* inputs = (const float*)d_in[0];   // [T,N,I]
    const float* wv     = (const float*)d_in[1];   // [H,I]
    const float* gamma  = (const float*)d_in[2];   // [H]
    const float* beta   = (const float*)d_in[3];   // [H]
    const float* wu     = (const float*)d_in[4];   // [O,H]
    const float* bu     = (const float*)d_in[5];   // [O]
    const float* mw     = (const float*)d_in[6];   // [K,H]

    float* out_h  = (float*)d_out;                           // [N,T,O] = 33.5M floats
    float* out_ph = out_h + (size_t)MROWS * O_DIM;           // [N,T,H] = 67M floats

    // p (bf16) parked in d_out's h-region: exactly MROWS*H*2 = 134,217,728 B
    unsigned short* p_b = (unsigned short*)d_out;

    char* ws = (char*)d_ws;
    unsigned short* ph_b  = (unsigned short*)ws;                     // 134,217,728 B
    unsigned short* in_b  = (unsigned short*)(ws + 134217728);       //  67,108,864 B
    unsigned short* wv_b  = (unsigned short*)(ws + 201326592);       //   4,194,304 B
    unsigned short* wu2_b = (unsigned short*)(ws + 205520896);       //   4,194,304 B
    float* sums   = (float*)(ws + 209715200);                        //      16,384 B
    float* sshift = (float*)(ws + 209731584);                        //      16,384 B
    float* bias2  = (float*)(ws + 209747968);                        //       4,096 B

    hipMemsetAsync(sums, 0, 2 * H_DIM * sizeof(float), stream);

    // 1. convert inputs / wv to bf16
    cvt_kernel<<<2048, 256, 0, stream>>>(inputs, in_b, (T_DIM * N_DIM * I_DIM) / 4);
    cvt_kernel<<<512, 256, 0, stream>>>(wv, wv_b, (H_DIM * I_DIM) / 4);

    // 2. GEMM1: p[n*T+t, h] = sum_i inputs[t,n,i]*wv[h,i]  -> bf16 scratch in d_out h-region
    dim3 g1(H_DIM / 128, MROWS / 128);
    gemm128<1, 0><<<g1, 256, 0, stream>>>(in_b, wv_b, (void*)p_b, nullptr, I_DIM, H_DIM);

    // 3. conv + p_hatt (fp32 out + bf16 copy) + BN partial sums
    conv_bn_stats<<<2048, 256, 0, stream>>>(p_b, mw, out_ph, ph_b, sums);

    // 4. BN finalize + fold into GEMM2 weights/bias
    bn_finalize<<<(H_DIM + 255) / 256, 256, 0, stream>>>(sums, gamma, beta, sshift);
    scale_wu<<<2048, 256, 0, stream>>>(wu, sshift, wu2_b);
    bias2_kernel<<<O_DIM, 256, 0, stream>>>(wu, sshift, bu, bias2);

    // 5. GEMM2: h = relu(ph_b @ wu2^T + bias2) -> overwrites p_b scratch (no longer needed)
    dim3 g2(O_DIM / 128, MROWS / 128);
    gemm128<0, 1><<<g2, 256, 0, stream>>>(ph_b, wu2_b, (void*)out_h, bias2, H_DIM, O_DIM);
}

// Round 2
// 611.352 us; speedup vs baseline: 1.6330x; 1.6330x over previous
//
#include <hip/hip_runtime.h>
#include <hip/hip_bf16.h>
#include <stdint.h>

// Problem constants (from setup_inputs)
#define T_DIM 2048
#define N_DIM 16
#define I_DIM 1024
#define H_DIM 2048
#define O_DIM 1024
#define K_TAPS 12
#define MROWS (N_DIM * T_DIM)   // 32768 rows of (n,t)
#define BN_EPS 1e-5f

// conv decomposition: subsample space per parity, length 1024
#define S_LEN 1024
#define TCHUNK 48
#define SCHUNKS 22              // ceil(1024/48)

typedef __attribute__((ext_vector_type(8))) short bf16x8;
typedef __attribute__((ext_vector_type(4))) float f32x4;

__device__ __forceinline__ unsigned short f2bf_rne(float f) {
    union { float f; unsigned u; } v; v.f = f;
    unsigned u = v.u;
    unsigned r = u + 0x7fffu + ((u >> 16) & 1u);
    return (unsigned short)(r >> 16);
}

__device__ __forceinline__ float bf2f(unsigned short x) {
    union { unsigned u; float f; } v; v.u = ((unsigned)x) << 16; return v.f;
}

// ---------------- fp32 -> bf16 conversion (vectorized x4) ----------------
__global__ void cvt_kernel(const float* __restrict__ in, unsigned short* __restrict__ out, int n4) {
    int i = blockIdx.x * blockDim.x + threadIdx.x;
    int stride = gridDim.x * blockDim.x;
    for (; i < n4; i += stride) {
        float4 v = ((const float4*)in)[i];
        ushort4 o;
        o.x = f2bf_rne(v.x); o.y = f2bf_rne(v.y);
        o.z = f2bf_rne(v.z); o.w = f2bf_rne(v.w);
        ((ushort4*)out)[i] = o;
    }
}

// ---------------- 128x128 bf16 MFMA GEMM, C = A * B^T ----------------
__device__ __forceinline__ void gload_lds16(const void* g, void* l) {
    __builtin_amdgcn_global_load_lds(
        (const __attribute__((address_space(1))) unsigned int*)g,
        (__attribute__((address_space(3))) unsigned int*)l, 16, 0, 0);
}

template<int PERM, int EPI>
__global__ __launch_bounds__(256) void gemm128(
    const unsigned short* __restrict__ A,
    const unsigned short* __restrict__ B,
    void* __restrict__ Cout,
    const float* __restrict__ bias,
    int Kd, int Ncols)
{
    __shared__ unsigned short As[2][128 * 32];
    __shared__ unsigned short Bs[2][128 * 32];

    const int tid = threadIdx.x;
    const long r0 = (long)blockIdx.y * 128;   // output row tile
    const long c0 = (long)blockIdx.x * 128;   // output col tile

    long aBase, aRowStride;
    if (PERM) {
        long n0 = r0 / T_DIM;
        long t0 = r0 % T_DIM;                 // tile stays within one n (T%128==0)
        aBase = (t0 * N_DIM + n0) * (long)Kd;
        aRowStride = (long)N_DIM * Kd;
    } else {
        aBase = r0 * (long)Kd;
        aRowStride = Kd;
    }
    const long bBase = c0 * (long)Kd;

    const int lrow  = tid >> 2;           // 0..63 (row within half-tile)
    const int lcolb = (tid & 3) * 16;     // byte col within 64B row

    f32x4 acc[4][4];
#pragma unroll
    for (int m = 0; m < 4; ++m)
#pragma unroll
        for (int n = 0; n < 4; ++n) acc[m][n] = (f32x4){0.f, 0.f, 0.f, 0.f};

    auto stage = [&](int buf, int kt) {
        const long k0 = (long)kt * 32;
#pragma unroll
        for (int i = 0; i < 2; ++i) {
            int row = i * 64 + lrow;
            const char* g = (const char*)(A + aBase + (long)row * aRowStride + k0) + lcolb;
            char* l = ((char*)&As[buf][0]) + i * 4096 + tid * 16;
            gload_lds16(g, l);
        }
#pragma unroll
        for (int i = 0; i < 2; ++i) {
            int row = i * 64 + lrow;
            const char* g = (const char*)(B + bBase + (long)row * (long)Kd + k0) + lcolb;
            char* l = ((char*)&Bs[buf][0]) + i * 4096 + tid * 16;
            gload_lds16(g, l);
        }
    };

    const int wv   = tid >> 6;            // wave 0..3
    const int lane = tid & 63;
    const int wr   = (wv >> 1) * 64;      // wave row offset
    const int wc   = (wv & 1) * 64;       // wave col offset
    const int fr   = lane & 15;
    const int kg   = (lane >> 4) * 8;     // k-offset (elems) within 32

    const int KT = Kd >> 5;
    int cur = 0;
    stage(0, 0);
    for (int kt = 0; kt < KT; ++kt) {
        __syncthreads();                   // staging of buf `cur` complete everywhere
        if (kt + 1 < KT) stage(cur ^ 1, kt + 1);
        bf16x8 af[4], bfr[4];
#pragma unroll
        for (int m = 0; m < 4; ++m)
            af[m] = *(const bf16x8*)&As[cur][(wr + m * 16 + fr) * 32 + kg];
#pragma unroll
        for (int n = 0; n < 4; ++n)
            bfr[n] = *(const bf16x8*)&Bs[cur][(wc + n * 16 + fr) * 32 + kg];
#pragma unroll
        for (int m = 0; m < 4; ++m)
#pragma unroll
            for (int n = 0; n < 4; ++n)
                acc[m][n] = __builtin_amdgcn_mfma_f32_16x16x32_bf16(af[m], bfr[n], acc[m][n], 0, 0, 0);
        cur ^= 1;
    }

    // C/D layout (m89-verified): col = lane&15, row = (lane>>4)*4 + reg
#pragma unroll
    for (int m = 0; m < 4; ++m) {
        const long orow_base = r0 + wr + m * 16 + ((lane >> 4) * 4);
#pragma unroll
        for (int n = 0; n < 4; ++n) {
            const long ocol = c0 + wc + n * 16 + fr;
#pragma unroll
            for (int j = 0; j < 4; ++j) {
                const long orow = orow_base + j;
                float vv = acc[m][n][j];
                if (EPI == 0) {
                    ((unsigned short*)Cout)[orow * Ncols + ocol] = f2bf_rne(vv);
                } else {
                    vv += bias[ocol];
                    vv = vv > 0.f ? vv : 0.f;
                    ((float*)Cout)[orow * Ncols + ocol] = vv;
                }
            }
        }
    }
}

// ---------------- depthwise dilated conv + BN stats, v2 ----------------
// All tap offsets (k-10)*2 are EVEN -> two independent dense 12-tap FIRs on
// the even/odd t-subsequences (subsample index s, length 1024 per parity).
// Each thread: 4 channels, TCHUNK=48 outputs, circular 12-slot fp32 window.
// Block: 256 threads cover 1024 channels (half of H); grid covers
// half(2) x chunk(22) x par(2) x n(16) = 1408 blocks.
__global__ __launch_bounds__(256) void conv_bn_v2(
    const unsigned short* __restrict__ p,   // [MROWS][H] bf16
    const float* __restrict__ w,            // [12][H]
    float* __restrict__ ph_f32,             // [MROWS][H] fp32 out
    unsigned short* __restrict__ ph_b,      // [MROWS][H] bf16 out
    float* __restrict__ sums)               // [2][H] zeroed
{
    const int tid   = threadIdx.x;
    const int b     = blockIdx.x;
    const int half  = b & 1;
    const int chunk = (b >> 1) % SCHUNKS;
    const int np    = (b >> 1) / SCHUNKS;
    const int par   = np & 1;
    const int n     = np >> 1;
    const int h0    = half * 1024 + tid * 4;

    float wk[12][4];
#pragma unroll
    for (int k = 0; k < 12; ++k) {
        float4 v = *(const float4*)&w[k * H_DIM + h0];
        wk[k][0] = v.x; wk[k][1] = v.y; wk[k][2] = v.z; wk[k][3] = v.w;
    }

    // base byte-layout: element index for (s) = b0 + s*2*H  (row stride in s is 2 rows)
    const long b0 = ((long)n * T_DIM + par) * (long)H_DIM + h0;
    const int s0 = chunk * TCHUNK;

    // win[(uu + j) % 12] holds x[s + j - 10] for current iteration; j=10 is x[s]
    float win[12][4];
#pragma unroll
    for (int j = 0; j < 12; ++j) {
        const int s = s0 + j - 10;
        if (s >= 0 && s < S_LEN) {
            ushort4 v = *(const ushort4*)&p[b0 + (long)s * (2 * H_DIM)];
            win[j][0] = bf2f(v.x); win[j][1] = bf2f(v.y);
            win[j][2] = bf2f(v.z); win[j][3] = bf2f(v.w);
        } else {
            win[j][0] = 0.f; win[j][1] = 0.f; win[j][2] = 0.f; win[j][3] = 0.f;
        }
    }

    float st1[4] = {0.f, 0.f, 0.f, 0.f};
    float st2[4] = {0.f, 0.f, 0.f, 0.f};

    for (int ss = 0; ss < TCHUNK; ss += 12) {
#pragma unroll
        for (int uu = 0; uu < 12; ++uu) {
            const int s = s0 + ss + uu;
            if (s < S_LEN) {                       // uniform across block
                float out[4];
#pragma unroll
                for (int c = 0; c < 4; ++c) out[c] = win[(uu + 10) % 12][c];
#pragma unroll
                for (int k = 0; k < 12; ++k)
#pragma unroll
                    for (int c = 0; c < 4; ++c)
                        out[c] += wk[k][c] * win[(uu + k) % 12][c];

                const long base = b0 + (long)s * (2 * H_DIM);
                *(float4*)&ph_f32[base] = make_float4(out[0], out[1], out[2], out[3]);
                ushort4 ob;
                ob.x = f2bf_rne(out[0]); ob.y = f2bf_rne(out[1]);
                ob.z = f2bf_rne(out[2]); ob.w = f2bf_rne(out[3]);
                *(ushort4*)&ph_b[base] = ob;
#pragma unroll
                for (int c = 0; c < 4; ++c) { st1[c] += out[c]; st2[c] += out[c] * out[c]; }
            }
            // shift: oldest slot (uu % 12) <- x[s+2]
            {
                const int sn = s0 + ss + uu + 2;   // >= 2, so only upper bound check
                if (sn < S_LEN) {
                    ushort4 v = *(const ushort4*)&p[b0 + (long)sn * (2 * H_DIM)];
                    win[uu][0] = bf2f(v.x); win[uu][1] = bf2f(v.y);
                    win[uu][2] = bf2f(v.z); win[uu][3] = bf2f(v.w);
                } else {
                    win[uu][0] = 0.f; win[uu][1] = 0.f; win[uu][2] = 0.f; win[uu][3] = 0.f;
                }
            }
        }
    }

#pragma unroll
    for (int c = 0; c < 4; ++c) {
        atomicAdd(&sums[h0 + c], st1[c]);
        atomicAdd(&sums[H_DIM + h0 + c], st2[c]);
    }
}

// ---------------- BN finalize: s = gamma*rsqrt(var+eps); shift = beta - mean*s ----
__global__ void bn_finalize(const float* __restrict__ sums,
                            const float* __restrict__ gamma,
                            const float* __restrict__ beta,
                            float* __restrict__ sshift) {
    int h = blockIdx.x * blockDim.x + threadIdx.x;
    if (h >= H_DIM) return;
    float mean = sums[h] * (1.f / (float)MROWS);
    float var  = sums[H_DIM + h] * (1.f / (float)MROWS) - mean * mean;
    float s = gamma[h] * rsqrtf(var + BN_EPS);
    sshift[h] = s;
    sshift[H_DIM + h] = beta[h] - mean * s;
}

// wu2[o,h] = bf16(wu[o,h] * s[h])
__global__ void scale_wu(const float* __restrict__ wu,
                         const float* __restrict__ sshift,
                         unsigned short* __restrict__ wu2) {
    int idx = blockIdx.x * blockDim.x + threadIdx.x;
    int stride = gridDim.x * blockDim.x;
    for (; idx < O_DIM * H_DIM; idx += stride) {
        int h = idx & (H_DIM - 1);
        wu2[idx] = f2bf_rne(wu[idx] * sshift[h]);
    }
}

// bias2[o] = bu[o] + sum_h shift[h]*wu[o,h]
__global__ __launch_bounds__(256) void bias2_kernel(
    const float* __restrict__ wu,
    const float* __restrict__ sshift,
    const float* __restrict__ bu,
    float* __restrict__ bias2) {
    const int o = blockIdx.x;
    float part = 0.f;
    for (int h = threadIdx.x; h < H_DIM; h += 256)
        part += sshift[H_DIM + h] * wu[(long)o * H_DIM + h];
#pragma unroll
    for (int off = 32; off > 0; off >>= 1) part += __shfl_down(part, off, 64);
    __shared__ float red[4];
    const int wv = threadIdx.x >> 6, lane = threadIdx.x & 63;
    if (lane == 0) red[wv] = part;
    __syncthreads();
    if (threadIdx.x == 0) bias2[o] = bu[o] + red[0] + red[1] + red[2] + red[3];
}

extern "C" void kernel_launch(void* const* d_in, const int* in_sizes, int n_in,
                              void* d_out, int out_size, void* d_ws, size_t ws_size,
                              hipStream_t stream) {
    const float* inputs = (const float*)d_in[0];   // [T,N,I]
    const float* wv     = (const float*)d_in[1];   // [H,I]
    const float* gamma  = (const float*)d_in[2];   // [H]
    const float* beta   = (const float*)d_in[3];   // [H]
    const float* wu     = (const float*)d_in[4];   // [O,H]
    const float* bu     = (const float*)d_in[5];   // [O]
    const float* mw     = (const float*)d_in[6];   // [K,H]

    float* out_h  = (float*)d_out;                           // [N,T,O] = 33.5M floats
    float* out_ph = out_h + (size_t)MROWS * O_DIM;           // [N,T,H] = 67M floats

    // p (bf16) parked in d_out's h-region: exactly MROWS*H*2 = 134,217,728 B
    unsigned short* p_b = (unsigned short*)d_out;

    char* ws = (char*)d_ws;
    unsigned short* ph_b  = (unsigned short*)ws;                     // 134,217,728 B
    unsigned short* in_b  = (unsigned short*)(ws + 134217728);       //  67,108,864 B
    unsigned short* wv_b  = (unsigned short*)(ws + 201326592);       //   4,194,304 B
    unsigned short* wu2_b = (unsigned short*)(ws + 205520896);       //   4,194,304 B
    float* sums   = (float*)(ws + 209715200);                        //      16,384 B
    float* sshift = (float*)(ws + 209731584);                        //      16,384 B
    float* bias2  = (float*)(ws + 209747968);                        //       4,096 B

    hipMemsetAsync(sums, 0, 2 * H_DIM * sizeof(float), stream);

    // 1. convert inputs / wv to bf16
    cvt_kernel<<<2048, 256, 0, stream>>>(inputs, in_b, (T_DIM * N_DIM * I_DIM) / 4);
    cvt_kernel<<<512, 256, 0, stream>>>(wv, wv_b, (H_DIM * I_DIM) / 4);

    // 2. GEMM1: p[n*T+t, h] = sum_i inputs[t,n,i]*wv[h,i]  -> bf16 scratch in d_out h-region
    dim3 g1(H_DIM / 128, MROWS / 128);
    gemm128<1, 0><<<g1, 256, 0, stream>>>(in_b, wv_b, (void*)p_b, nullptr, I_DIM, H_DIM);

    // 3. conv + p_hatt (fp32 out + bf16 copy) + BN partial sums
    conv_bn_v2<<<2 * SCHUNKS * 2 * N_DIM, 256, 0, stream>>>(p_b, mw, out_ph, ph_b, sums);

    // 4. BN finalize + fold into GEMM2 weights/bias
    bn_finalize<<<(H_DIM + 255) / 256, 256, 0, stream>>>(sums, gamma, beta, sshift);
    scale_wu<<<2048, 256, 0, stream>>>(wu, sshift, wu2_b);
    bias2_kernel<<<O_DIM, 256, 0, stream>>>(wu, sshift, bu, bias2);

    // 5. GEMM2: h = relu(ph_b @ wu2^T + bias2) -> overwrites p_b scratch (no longer needed)
    dim3 g2(O_DIM / 128, MROWS / 128);
    gemm128<0, 1><<<g2, 256, 0, stream>>>(ph_b, wu2_b, (void*)out_h, bias2, H_DIM, O_DIM);
}

// Round 4
// 460.899 us; speedup vs baseline: 2.1661x; 1.3264x over previous
//
#include <hip/hip_runtime.h>
#include <hip/hip_bf16.h>
#include <stdint.h>

// Problem constants (from setup_inputs)
#define T_DIM 2048
#define N_DIM 16
#define I_DIM 1024
#define H_DIM 2048
#define O_DIM 1024
#define K_TAPS 12
#define MROWS (N_DIM * T_DIM)   // 32768 rows of (n,t)
#define BN_EPS 1e-5f

// conv decomposition: subsample space per parity, length 1024
#define S_LEN 1024
#define TCHUNK 48
#define SCHUNKS 22              // ceil(1024/48)

typedef __attribute__((ext_vector_type(8))) short bf16x8;
typedef __attribute__((ext_vector_type(4))) float f32x4;

__device__ __forceinline__ unsigned short f2bf_rne(float f) {
    union { float f; unsigned u; } v; v.f = f;
    unsigned u = v.u;
    unsigned r = u + 0x7fffu + ((u >> 16) & 1u);
    return (unsigned short)(r >> 16);
}

__device__ __forceinline__ float bf2f(unsigned short x) {
    union { unsigned u; float f; } v; v.u = ((unsigned)x) << 16; return v.f;
}

// ---------------- fp32 -> bf16 conversion (vectorized x4) ----------------
__global__ void cvt_kernel(const float* __restrict__ in, unsigned short* __restrict__ out, int n4) {
    int i = blockIdx.x * blockDim.x + threadIdx.x;
    int stride = gridDim.x * blockDim.x;
    for (; i < n4; i += stride) {
        float4 v = ((const float4*)in)[i];
        ushort4 o;
        o.x = f2bf_rne(v.x); o.y = f2bf_rne(v.y);
        o.z = f2bf_rne(v.z); o.w = f2bf_rne(v.w);
        ((ushort4*)out)[i] = o;
    }
}

__device__ __forceinline__ void gload_lds16(const void* g, void* l) {
    __builtin_amdgcn_global_load_lds(
        (const __attribute__((address_space(1))) unsigned int*)g,
        (__attribute__((address_space(3))) unsigned int*)l, 16, 0, 0);
}

// ---------------- 256x256 8-phase bf16 MFMA GEMM, C = A * B^T ----------------
// 512 threads = 8 waves (2 M x 4 N), per-wave output 128x64, BK=64, 2-deep LDS dbuf.
// T2 read-swizzle: lds_byte(row, blk16) = row*128 + ((blk16 ^ (row&7))<<4);
// staging applies the inverse permutation on the GLOBAL source (linear LDS dest).
// Waits: vmcnt(2)+barrier at phases 0 and 4 only (counted, never drain in main loop).
template<int PERM, int EPI, int KD, int NCOLS>
__global__ __launch_bounds__(512, 2) void gemm256(
    const unsigned short* __restrict__ A,
    const unsigned short* __restrict__ B,
    void* __restrict__ Cout,
    const float* __restrict__ bias)
{
    __shared__ char lds[131072];   // buf b: A at b*65536, B at b*65536+32768

    const int tid  = threadIdx.x;
    const int wid  = tid >> 6;
    const int lane = tid & 63;
    const int wr   = (wid >> 2) * 128;    // wave row offset (2 warps_m)
    const int wc   = (wid & 3) * 64;      // wave col offset (4 warps_n)
    const int fr   = lane & 15;
    const int fh   = lane >> 4;           // 0..3

    // XCD-aware bijective swizzle (nwg % 8 == 0 for both launches)
    const int nwg = gridDim.x;
    const int lin = blockIdx.x;
    const int tile = (lin & 7) * (nwg >> 3) + (lin >> 3);
    const int ntx = NCOLS / 256;
    const long c0 = (long)(tile % ntx) * 256;
    const long r0 = (long)(tile / ntx) * 256;

    long aBase, aStride;
    if (PERM) {
        const long n0 = r0 / T_DIM;
        const long t0 = r0 % T_DIM;       // 256-row tile stays within one n
        aBase = (t0 * N_DIM + n0) * (long)KD;
        aStride = (long)N_DIM * KD;
    } else {
        aBase = r0 * (long)KD;
        aStride = KD;
    }
    const long bBase = c0 * (long)KD;

    // stage one half-tile (128 rows x 64 cols) of A or B: 2 x global_load_lds(16B).
    // LDS dest must include the h offset so halves don't alias:
    //   dest = mbase + h*16384 + j*8192 + tid*16  ->  row*128 + (tid&7)*16 exactly.
    auto stage_half = [&](int buf, int mat, int h, int kt) {
        char* mbase = lds + buf * 65536 + mat * 32768 + h * 16384;
#pragma unroll
        for (int j = 0; j < 2; ++j) {
            const int row = h * 128 + j * 64 + (tid >> 3);
            const int g   = (tid & 7) ^ (row & 7);      // inverse swizzle on source
            long gelem;
            if (mat == 0) gelem = aBase + (long)row * aStride + (long)kt * 64 + g * 8;
            else          gelem = bBase + (long)row * (long)KD + (long)kt * 64 + g * 8;
            gload_lds16((const char*)(mat == 0 ? A : B) + gelem * 2,
                        mbase + j * 8192 + tid * 16);
        }
    };

    auto rdA = [&](int buf, int m, int ks) -> bf16x8 {
        const int row = wr + m * 16 + fr;
        const int blk = ks * 4 + fh;
        return *(const bf16x8*)(lds + buf * 65536 + row * 128 + ((blk ^ (row & 7)) << 4));
    };
    auto rdB = [&](int buf, int n, int ks) -> bf16x8 {
        const int row = wc + n * 16 + fr;
        const int blk = ks * 4 + fh;
        return *(const bf16x8*)(lds + buf * 65536 + 32768 + row * 128 + ((blk ^ (row & 7)) << 4));
    };

    f32x4 acc[8][4] = {};

    // prologue: stage tile 0 into buf0 (8 loads/thread)
    stage_half(0, 0, 0, 0); stage_half(0, 0, 1, 0);
    stage_half(0, 1, 0, 0); stage_half(0, 1, 1, 0);

    const int KT  = KD / 64;
    const int KT2 = KT / 2;
    for (int i = 0; i < KT2; ++i) {
        const int tB = 2 * i + 1;
        const bool haveNext = (i + 1 < KT2);
        bf16x8 bfr[4][2];

        // ---- phases 0-3: compute tile 2i from buf0; stage tile 2i+1 into buf1
#pragma unroll
        for (int q = 0; q < 4; ++q) {
            stage_half(1, q >> 1, q & 1, tB);
            bf16x8 af[2][2];
            if (q == 0) {
                asm volatile("s_waitcnt vmcnt(2)" ::: "memory");
                __builtin_amdgcn_s_barrier();
#pragma unroll
                for (int n = 0; n < 4; ++n)
#pragma unroll
                    for (int ks = 0; ks < 2; ++ks) bfr[n][ks] = rdB(0, n, ks);
#pragma unroll
                for (int mm = 0; mm < 2; ++mm)
#pragma unroll
                    for (int ks = 0; ks < 2; ++ks) af[mm][ks] = rdA(0, q * 2 + mm, ks);
            } else {
#pragma unroll
                for (int mm = 0; mm < 2; ++mm)
#pragma unroll
                    for (int ks = 0; ks < 2; ++ks) af[mm][ks] = rdA(0, q * 2 + mm, ks);
                __builtin_amdgcn_s_barrier();
            }
            __builtin_amdgcn_s_setprio(1);
#pragma unroll
            for (int mm = 0; mm < 2; ++mm)
#pragma unroll
                for (int n = 0; n < 4; ++n)
#pragma unroll
                    for (int ks = 0; ks < 2; ++ks)
                        acc[q * 2 + mm][n] = __builtin_amdgcn_mfma_f32_16x16x32_bf16(
                            af[mm][ks], bfr[n][ks], acc[q * 2 + mm][n], 0, 0, 0);
            __builtin_amdgcn_s_setprio(0);
            __builtin_amdgcn_s_barrier();
        }

        // ---- phases 4-7: compute tile 2i+1 from buf1; stage tile 2i+2 into buf0
#pragma unroll
        for (int q = 0; q < 4; ++q) {
            if (haveNext) stage_half(0, q >> 1, q & 1, 2 * i + 2);
            bf16x8 af[2][2];
            if (q == 0) {
                if (haveNext) asm volatile("s_waitcnt vmcnt(2)" ::: "memory");
                else          asm volatile("s_waitcnt vmcnt(0)" ::: "memory");
                __builtin_amdgcn_s_barrier();
#pragma unroll
                for (int n = 0; n < 4; ++n)
#pragma unroll
                    for (int ks = 0; ks < 2; ++ks) bfr[n][ks] = rdB(1, n, ks);
#pragma unroll
                for (int mm = 0; mm < 2; ++mm)
#pragma unroll
                    for (int ks = 0; ks < 2; ++ks) af[mm][ks] = rdA(1, q * 2 + mm, ks);
            } else {
#pragma unroll
                for (int mm = 0; mm < 2; ++mm)
#pragma unroll
                    for (int ks = 0; ks < 2; ++ks) af[mm][ks] = rdA(1, q * 2 + mm, ks);
                __builtin_amdgcn_s_barrier();
            }
            __builtin_amdgcn_s_setprio(1);
#pragma unroll
            for (int mm = 0; mm < 2; ++mm)
#pragma unroll
                for (int n = 0; n < 4; ++n)
#pragma unroll
                    for (int ks = 0; ks < 2; ++ks)
                        acc[q * 2 + mm][n] = __builtin_amdgcn_mfma_f32_16x16x32_bf16(
                            af[mm][ks], bfr[n][ks], acc[q * 2 + mm][n], 0, 0, 0);
            __builtin_amdgcn_s_setprio(0);
            __builtin_amdgcn_s_barrier();
        }
    }

    // epilogue: C/D layout col = lane&15, row = (lane>>4)*4 + j
#pragma unroll
    for (int m = 0; m < 8; ++m) {
        const long orow_base = r0 + wr + m * 16 + fh * 4;
#pragma unroll
        for (int n = 0; n < 4; ++n) {
            const long ocol = c0 + wc + n * 16 + fr;
#pragma unroll
            for (int j = 0; j < 4; ++j) {
                const long orow = orow_base + j;
                float vv = acc[m][n][j];
                if (EPI == 0) {
                    ((unsigned short*)Cout)[orow * NCOLS + ocol] = f2bf_rne(vv);
                } else {
                    vv += bias[ocol];
                    vv = vv > 0.f ? vv : 0.f;
                    ((float*)Cout)[orow * NCOLS + ocol] = vv;
                }
            }
        }
    }
}

// ---------------- depthwise dilated conv + BN stats, v2 ----------------
__global__ __launch_bounds__(256) void conv_bn_v2(
    const unsigned short* __restrict__ p,   // [MROWS][H] bf16
    const float* __restrict__ w,            // [12][H]
    float* __restrict__ ph_f32,             // [MROWS][H] fp32 out
    unsigned short* __restrict__ ph_b,      // [MROWS][H] bf16 out
    float* __restrict__ sums)               // [2][H] zeroed
{
    const int tid   = threadIdx.x;
    const int b     = blockIdx.x;
    const int half  = b & 1;
    const int chunk = (b >> 1) % SCHUNKS;
    const int np    = (b >> 1) / SCHUNKS;
    const int par   = np & 1;
    const int n     = np >> 1;
    const int h0    = half * 1024 + tid * 4;

    float wk[12][4];
#pragma unroll
    for (int k = 0; k < 12; ++k) {
        float4 v = *(const float4*)&w[k * H_DIM + h0];
        wk[k][0] = v.x; wk[k][1] = v.y; wk[k][2] = v.z; wk[k][3] = v.w;
    }

    const long b0 = ((long)n * T_DIM + par) * (long)H_DIM + h0;
    const int s0 = chunk * TCHUNK;

    float win[12][4];
#pragma unroll
    for (int j = 0; j < 12; ++j) {
        const int s = s0 + j - 10;
        if (s >= 0 && s < S_LEN) {
            ushort4 v = *(const ushort4*)&p[b0 + (long)s * (2 * H_DIM)];
            win[j][0] = bf2f(v.x); win[j][1] = bf2f(v.y);
            win[j][2] = bf2f(v.z); win[j][3] = bf2f(v.w);
        } else {
            win[j][0] = 0.f; win[j][1] = 0.f; win[j][2] = 0.f; win[j][3] = 0.f;
        }
    }

    float st1[4] = {0.f, 0.f, 0.f, 0.f};
    float st2[4] = {0.f, 0.f, 0.f, 0.f};

    for (int ss = 0; ss < TCHUNK; ss += 12) {
#pragma unroll
        for (int uu = 0; uu < 12; ++uu) {
            const int s = s0 + ss + uu;
            if (s < S_LEN) {
                float out[4];
#pragma unroll
                for (int c = 0; c < 4; ++c) out[c] = win[(uu + 10) % 12][c];
#pragma unroll
                for (int k = 0; k < 12; ++k)
#pragma unroll
                    for (int c = 0; c < 4; ++c)
                        out[c] += wk[k][c] * win[(uu + k) % 12][c];

                const long base = b0 + (long)s * (2 * H_DIM);
                *(float4*)&ph_f32[base] = make_float4(out[0], out[1], out[2], out[3]);
                ushort4 ob;
                ob.x = f2bf_rne(out[0]); ob.y = f2bf_rne(out[1]);
                ob.z = f2bf_rne(out[2]); ob.w = f2bf_rne(out[3]);
                *(ushort4*)&ph_b[base] = ob;
#pragma unroll
                for (int c = 0; c < 4; ++c) { st1[c] += out[c]; st2[c] += out[c] * out[c]; }
            }
            {
                const int sn = s0 + ss + uu + 2;
                if (sn < S_LEN) {
                    ushort4 v = *(const ushort4*)&p[b0 + (long)sn * (2 * H_DIM)];
                    win[uu][0] = bf2f(v.x); win[uu][1] = bf2f(v.y);
                    win[uu][2] = bf2f(v.z); win[uu][3] = bf2f(v.w);
                } else {
                    win[uu][0] = 0.f; win[uu][1] = 0.f; win[uu][2] = 0.f; win[uu][3] = 0.f;
                }
            }
        }
    }

#pragma unroll
    for (int c = 0; c < 4; ++c) {
        atomicAdd(&sums[h0 + c], st1[c]);
        atomicAdd(&sums[H_DIM + h0 + c], st2[c]);
    }
}

// ---------------- BN finalize: s = gamma*rsqrt(var+eps); shift = beta - mean*s ----
__global__ void bn_finalize(const float* __restrict__ sums,
                            const float* __restrict__ gamma,
                            const float* __restrict__ beta,
                            float* __restrict__ sshift) {
    int h = blockIdx.x * blockDim.x + threadIdx.x;
    if (h >= H_DIM) return;
    float mean = sums[h] * (1.f / (float)MROWS);
    float var  = sums[H_DIM + h] * (1.f / (float)MROWS) - mean * mean;
    float s = gamma[h] * rsqrtf(var + BN_EPS);
    sshift[h] = s;
    sshift[H_DIM + h] = beta[h] - mean * s;
}

// wu2[o,h] = bf16(wu[o,h] * s[h])
__global__ void scale_wu(const float* __restrict__ wu,
                         const float* __restrict__ sshift,
                         unsigned short* __restrict__ wu2) {
    int idx = blockIdx.x * blockDim.x + threadIdx.x;
    int stride = gridDim.x * blockDim.x;
    for (; idx < O_DIM * H_DIM; idx += stride) {
        int h = idx & (H_DIM - 1);
        wu2[idx] = f2bf_rne(wu[idx] * sshift[h]);
    }
}

// bias2[o] = bu[o] + sum_h shift[h]*wu[o,h]
__global__ __launch_bounds__(256) void bias2_kernel(
    const float* __restrict__ wu,
    const float* __restrict__ sshift,
    const float* __restrict__ bu,
    float* __restrict__ bias2) {
    const int o = blockIdx.x;
    float part = 0.f;
    for (int h = threadIdx.x; h < H_DIM; h += 256)
        part += sshift[H_DIM + h] * wu[(long)o * H_DIM + h];
#pragma unroll
    for (int off = 32; off > 0; off >>= 1) part += __shfl_down(part, off, 64);
    __shared__ float red[4];
    const int wv = threadIdx.x >> 6, lane = threadIdx.x & 63;
    if (lane == 0) red[wv] = part;
    __syncthreads();
    if (threadIdx.x == 0) bias2[o] = bu[o] + red[0] + red[1] + red[2] + red[3];
}

extern "C" void kernel_launch(void* const* d_in, const int* in_sizes, int n_in,
                              void* d_out, int out_size, void* d_ws, size_t ws_size,
                              hipStream_t stream) {
    const float* inputs = (const float*)d_in[0];   // [T,N,I]
    const float* wv     = (const float*)d_in[1];   // [H,I]
    const float* gamma  = (const float*)d_in[2];   // [H]
    const float* beta   = (const float*)d_in[3];   // [H]
    const float* wu     = (const float*)d_in[4];   // [O,H]
    const float* bu     = (const float*)d_in[5];   // [O]
    const float* mw     = (const float*)d_in[6];   // [K,H]

    float* out_h  = (float*)d_out;                           // [N,T,O] = 33.5M floats
    float* out_ph = out_h + (size_t)MROWS * O_DIM;           // [N,T,H] = 67M floats

    // p (bf16) parked in d_out's h-region: exactly MROWS*H*2 = 134,217,728 B
    unsigned short* p_b = (unsigned short*)d_out;

    char* ws = (char*)d_ws;
    unsigned short* ph_b  = (unsigned short*)ws;                     // 134,217,728 B
    unsigned short* in_b  = (unsigned short*)(ws + 134217728);       //  67,108,864 B
    unsigned short* wv_b  = (unsigned short*)(ws + 201326592);       //   4,194,304 B
    unsigned short* wu2_b = (unsigned short*)(ws + 205520896);       //   4,194,304 B
    float* sums   = (float*)(ws + 209715200);                        //      16,384 B
    float* sshift = (float*)(ws + 209731584);                        //      16,384 B
    float* bias2  = (float*)(ws + 209747968);                        //       4,096 B

    hipMemsetAsync(sums, 0, 2 * H_DIM * sizeof(float), stream);

    // 1. convert inputs / wv to bf16
    cvt_kernel<<<2048, 256, 0, stream>>>(inputs, in_b, (T_DIM * N_DIM * I_DIM) / 4);
    cvt_kernel<<<512, 256, 0, stream>>>(wv, wv_b, (H_DIM * I_DIM) / 4);

    // 2. GEMM1: p[n*T+t, h] = sum_i inputs[t,n,i]*wv[h,i] -> bf16 in d_out h-region
    gemm256<1, 0, I_DIM, H_DIM><<<(MROWS / 256) * (H_DIM / 256), 512, 0, stream>>>(
        in_b, wv_b, (void*)p_b, nullptr);

    // 3. conv + p_hatt (fp32 out + bf16 copy) + BN partial sums
    conv_bn_v2<<<2 * SCHUNKS * 2 * N_DIM, 256, 0, stream>>>(p_b, mw, out_ph, ph_b, sums);

    // 4. BN finalize + fold into GEMM2 weights/bias
    bn_finalize<<<(H_DIM + 255) / 256, 256, 0, stream>>>(sums, gamma, beta, sshift);
    scale_wu<<<2048, 256, 0, stream>>>(wu, sshift, wu2_b);
    bias2_kernel<<<O_DIM, 256, 0, stream>>>(wu, sshift, bu, bias2);

    // 5. GEMM2: h = relu(ph_b @ wu2^T + bias2) -> out_h
    gemm256<0, 1, H_DIM, O_DIM><<<(MROWS / 256) * (O_DIM / 256), 512, 0, stream>>>(
        ph_b, wu2_b, (void*)out_h, bias2);
}